// Round 1
// baseline (15100.876 us; speedup 1.0000x reference)
//
#include <hip/hip_runtime.h>
#include <hip/hip_bf16.h>

// ---------------------------------------------------------------------------
// HazardGNN: h = emb[kinds]; 3x { m = MLP(h[src]|h[dst]|ea); agg = segsum(m,dst);
// h = GRUCell(agg, h) }; out = sigmoid(head(h[src]|h[dst]|ea))
// Baseline: fp32, thread-per-edge, k-outer with 64 accumulators, scalar-load
// weights (pre-transposed into ws), fp32 global atomics for segment_sum.
// ---------------------------------------------------------------------------

#define D_NODE 64
#define D_MSG  64
#define D_IN   132   // 64 + 64 + 4

__device__ __forceinline__ float fast_sig(float x) {
    return 1.f / (1.f + __expf(-x));
}
__device__ __forceinline__ float fast_tanh(float x) {
    float ax = fabsf(x);
    float t = __expf(-2.f * ax);
    float r = (1.f - t) / (1.f + t);
    return copysignf(r, x);
}

// ---------------------------------------------------------------------------
// prep: transpose weights once per launch.
//  msgW1T[l][k][j] (k<132,j<64)    <- msg_w1[l][j][k]
//  msgW2T[l][k][j] (k<64, j<64)    <- msg_w2[l][j][k]
//  wihT/whhT packed [l][g][kc][j][ks] <- w[l][g*64+j][kc*4+ks]  (coalesced f4)
//  headW1T[k][j]                   <- head_w1[j][k]
// ---------------------------------------------------------------------------
__global__ void prep_kernel(const float* __restrict__ msg_w1,
                            const float* __restrict__ msg_w2,
                            const float* __restrict__ gru_wih,
                            const float* __restrict__ gru_whh,
                            const float* __restrict__ head_w1,
                            float* __restrict__ msgW1T, float* __restrict__ msgW2T,
                            float* __restrict__ wihT, float* __restrict__ whhT,
                            float* __restrict__ headW1T) {
    int t = blockIdx.x * 256 + threadIdx.x;
    if (t < 3 * 8448) {  // msg W1T
        int l = t / 8448, r = t % 8448, k = r / 64, j = r % 64;
        msgW1T[t] = msg_w1[l * 8448 + j * 132 + k];
        return;
    }
    t -= 3 * 8448;
    if (t < 3 * 4096) {  // msg W2T
        int l = t / 4096, r = t % 4096, k = r / 64, j = r % 64;
        msgW2T[t] = msg_w2[l * 4096 + j * 64 + k];
        return;
    }
    t -= 3 * 4096;
    if (t < 3 * 12288) {  // wihT packed
        int l = t / 12288, r = t % 12288;
        int ks = r & 3, j = (r >> 2) & 63, kcg = r >> 8;
        int kc = kcg & 15, g = kcg >> 4;
        wihT[t] = gru_wih[l * 12288 + (g * 64 + j) * 64 + kc * 4 + ks];
        return;
    }
    t -= 3 * 12288;
    if (t < 3 * 12288) {  // whhT packed
        int l = t / 12288, r = t % 12288;
        int ks = r & 3, j = (r >> 2) & 63, kcg = r >> 8;
        int kc = kcg & 15, g = kcg >> 4;
        whhT[t] = gru_whh[l * 12288 + (g * 64 + j) * 64 + kc * 4 + ks];
        return;
    }
    t -= 3 * 12288;
    if (t < 8448) {  // head W1T
        int k = t / 64, j = t % 64;
        headW1T[t] = head_w1[j * 132 + k];
    }
}

// h[n][d] = emb[kind[n]][d], one float4 per thread
__global__ void embed_kernel(float* __restrict__ h, const float* __restrict__ emb,
                             const int* __restrict__ kinds, int N) {
    int t = blockIdx.x * 256 + threadIdx.x;
    if (t >= N * 16) return;
    int n = t >> 4, q = t & 15;
    ((float4*)h)[t] = ((const float4*)emb)[kinds[n] * 16 + q];
}

// shared first-layer MLP: acc[j] = silu( sum_k W1T[k][j] * x[k] + b1[j] )
// x = [h[src] (64) | h[dst] (64) | edge_attr (4)]
__device__ __forceinline__ void mlp132(const float4* __restrict__ hs4,
                                       const float4* __restrict__ hd4,
                                       float4 eattr,
                                       const float* __restrict__ W1T,
                                       const float* __restrict__ b1,
                                       float acc[64]) {
#pragma unroll
    for (int j = 0; j < 64; j++) acc[j] = b1[j];
#pragma unroll
    for (int c = 0; c < 16; c++) {
        float4 x = hs4[c];
        const float* w = W1T + c * 256;  // rows k = 4c..4c+3
#pragma unroll
        for (int j = 0; j < 64; j++)
            acc[j] += w[j] * x.x + w[64 + j] * x.y + w[128 + j] * x.z + w[192 + j] * x.w;
    }
#pragma unroll
    for (int c = 0; c < 16; c++) {
        float4 x = hd4[c];
        const float* w = W1T + 4096 + c * 256;  // rows k = 64+4c..
#pragma unroll
        for (int j = 0; j < 64; j++)
            acc[j] += w[j] * x.x + w[64 + j] * x.y + w[128 + j] * x.z + w[192 + j] * x.w;
    }
    {
        float4 x = eattr;
        const float* w = W1T + 8192;  // rows k = 128..131
#pragma unroll
        for (int j = 0; j < 64; j++)
            acc[j] += w[j] * x.x + w[64 + j] * x.y + w[128 + j] * x.z + w[192 + j] * x.w;
    }
#pragma unroll
    for (int j = 0; j < 64; j++) {
        float v = acc[j];
        acc[j] = v / (1.f + __expf(-v));  // silu
    }
}

// per-edge message + scatter-add into agg[dst]
__global__ __launch_bounds__(256) void edge_msg_kernel(
    const float* __restrict__ h, const int* __restrict__ src,
    const int* __restrict__ dst, const float* __restrict__ ea,
    const float* __restrict__ W1T, const float* __restrict__ b1,
    const float* __restrict__ W2T, const float* __restrict__ b2,
    float* __restrict__ agg, int E) {
    int e = blockIdx.x * 256 + threadIdx.x;
    if (e >= E) return;
    int s = src[e], d = dst[e];
    const float4* hs4 = (const float4*)(h + (size_t)s * 64);
    const float4* hd4 = (const float4*)(h + (size_t)d * 64);
    float4 eattr = ((const float4*)ea)[e];

    float hid[64];
    mlp132(hs4, hd4, eattr, W1T, b1, hid);

    float m[64];
#pragma unroll
    for (int j = 0; j < 64; j++) m[j] = b2[j];
#pragma unroll
    for (int k = 0; k < 64; k++) {
        const float* w = W2T + k * 64;
        float xk = hid[k];
#pragma unroll
        for (int j = 0; j < 64; j++) m[j] += w[j] * xk;
    }
    float* aggd = agg + (size_t)d * 64;
#pragma unroll
    for (int j = 0; j < 64; j++) unsafeAtomicAdd(aggd + j, m[j]);
}

// GRU: 4 nodes per block; thread (node, j). agg/h rows staged in LDS.
__global__ __launch_bounds__(256) void gru_kernel(
    float* __restrict__ h, const float* __restrict__ agg,
    const float* __restrict__ wihT, const float* __restrict__ whhT,
    const float* __restrict__ bih, const float* __restrict__ bhh, int N) {
    int w = threadIdx.x >> 6, j = threadIdx.x & 63;
    int node = blockIdx.x * 4 + w;
    __shared__ float4 sa[4][16], sh[4][16];
    bool valid = node < N;
    if (valid && j < 16) sa[w][j] = ((const float4*)(agg + (size_t)node * 64))[j];
    if (valid && j >= 16 && j < 32) sh[w][j - 16] = ((const float4*)(h + (size_t)node * 64))[j - 16];
    __syncthreads();

    float accR = 0.f, accZ = 0.f, accI = 0.f, accH = 0.f;
    const float4* wi = (const float4*)wihT;
    const float4* wh = (const float4*)whhT;
#pragma unroll
    for (int kc = 0; kc < 16; kc++) {
        float4 a = sa[w][kc], hh = sh[w][kc];
        float4 t;
        t = wi[(0 * 16 + kc) * 64 + j]; accR += t.x * a.x + t.y * a.y + t.z * a.z + t.w * a.w;
        t = wh[(0 * 16 + kc) * 64 + j]; accR += t.x * hh.x + t.y * hh.y + t.z * hh.z + t.w * hh.w;
        t = wi[(1 * 16 + kc) * 64 + j]; accZ += t.x * a.x + t.y * a.y + t.z * a.z + t.w * a.w;
        t = wh[(1 * 16 + kc) * 64 + j]; accZ += t.x * hh.x + t.y * hh.y + t.z * hh.z + t.w * hh.w;
        t = wi[(2 * 16 + kc) * 64 + j]; accI += t.x * a.x + t.y * a.y + t.z * a.z + t.w * a.w;
        t = wh[(2 * 16 + kc) * 64 + j]; accH += t.x * hh.x + t.y * hh.y + t.z * hh.z + t.w * hh.w;
    }
    float r = fast_sig(accR + bih[j] + bhh[j]);
    float z = fast_sig(accZ + bih[64 + j] + bhh[64 + j]);
    float n = fast_tanh(accI + bih[128 + j] + r * (accH + bhh[128 + j]));
    if (valid) {
        float ho = ((const float*)&sh[w][0])[j];
        h[(size_t)node * 64 + j] = (1.f - z) * n + z * ho;
    }
}

// edge head: logit = hw2 . silu(W1T x + b1) + hb2; out = sigmoid(logit)
__global__ __launch_bounds__(256) void head_kernel(
    const float* __restrict__ h, const int* __restrict__ src,
    const int* __restrict__ dst, const float* __restrict__ ea,
    const float* __restrict__ W1T, const float* __restrict__ b1,
    const float* __restrict__ hw2, const float* __restrict__ hb2,
    float* __restrict__ out, int E) {
    int e = blockIdx.x * 256 + threadIdx.x;
    if (e >= E) return;
    int s = src[e], d = dst[e];
    const float4* hs4 = (const float4*)(h + (size_t)s * 64);
    const float4* hd4 = (const float4*)(h + (size_t)d * 64);
    float4 eattr = ((const float4*)ea)[e];

    float hid[64];
    mlp132(hs4, hd4, eattr, W1T, b1, hid);

    float logit = hb2[0];
#pragma unroll
    for (int k = 0; k < 64; k++) logit += hw2[k] * hid[k];
    out[e] = fast_sig(logit);
}

extern "C" void kernel_launch(void* const* d_in, const int* in_sizes, int n_in,
                              void* d_out, int out_size, void* d_ws, size_t ws_size,
                              hipStream_t stream) {
    const int* edge_index = (const int*)d_in[0];
    int E = in_sizes[0] / 2;
    const int* src = edge_index;
    const int* dst = edge_index + E;
    const int* kinds = (const int*)d_in[1];
    int N = in_sizes[1];
    const float* edge_attr = (const float*)d_in[2];
    const float* emb = (const float*)d_in[3];
    const float* msg_w1 = (const float*)d_in[4];
    const float* msg_b1 = (const float*)d_in[5];
    const float* msg_w2 = (const float*)d_in[6];
    const float* msg_b2 = (const float*)d_in[7];
    const float* gru_wih = (const float*)d_in[8];
    const float* gru_whh = (const float*)d_in[9];
    const float* gru_bih = (const float*)d_in[10];
    const float* gru_bhh = (const float*)d_in[11];
    const float* head_w1 = (const float*)d_in[12];
    const float* head_b1 = (const float*)d_in[13];
    const float* head_w2 = (const float*)d_in[14];
    const float* head_b2 = (const float*)d_in[15];
    float* out = (float*)d_out;

    // workspace carve-up (floats)
    float* ws = (float*)d_ws;
    float* h = ws;                            // N*64
    float* agg = h + (size_t)N * 64;          // N*64
    float* msgW1T = agg + (size_t)N * 64;     // 3*8448
    float* msgW2T = msgW1T + 3 * 8448;        // 3*4096
    float* wihT = msgW2T + 3 * 4096;          // 3*12288
    float* whhT = wihT + 3 * 12288;           // 3*12288
    float* headW1T = whhT + 3 * 12288;        // 8448

    // 25344 + 12288 + 36864 + 36864 + 8448 = 119808 = 468 * 256
    prep_kernel<<<468, 256, 0, stream>>>(msg_w1, msg_w2, gru_wih, gru_whh, head_w1,
                                         msgW1T, msgW2T, wihT, whhT, headW1T);
    embed_kernel<<<(N * 16 + 255) / 256, 256, 0, stream>>>(h, emb, kinds, N);

    for (int l = 0; l < 3; l++) {
        hipMemsetAsync(agg, 0, (size_t)N * 64 * sizeof(float), stream);
        edge_msg_kernel<<<(E + 255) / 256, 256, 0, stream>>>(
            h, src, dst, edge_attr,
            msgW1T + l * 8448, msg_b1 + l * 64,
            msgW2T + l * 4096, msg_b2 + l * 64, agg, E);
        gru_kernel<<<(N + 3) / 4, 256, 0, stream>>>(
            h, agg, wihT + l * 12288, whhT + l * 12288,
            gru_bih + l * 192, gru_bhh + l * 192, N);
    }
    head_kernel<<<(E + 255) / 256, 256, 0, stream>>>(
        h, src, dst, edge_attr, headW1T, head_b1, head_w2, head_b2, out, E);
}

// Round 2
// 11013.822 us; speedup vs baseline: 1.3711x; 1.3711x over previous
//
#include <hip/hip_runtime.h>
#include <hip/hip_bf16.h>

// ---------------------------------------------------------------------------
// HazardGNN. Round 1: edges counting-sorted by dst once per launch; edge_msg
// kernel runs in dst-sorted order and does a wave-level segmented reduction
// (distance-guarded Hillis-Steele over shfl_up) so only segment-tail lanes
// issue fp32 atomics (~5 lanes/wave instead of 64). Compute stays fp32.
// ---------------------------------------------------------------------------

#define D_NODE 64
#define D_MSG  64
#define D_IN   132   // 64 + 64 + 4

__device__ __forceinline__ float fast_sig(float x) {
    return 1.f / (1.f + __expf(-x));
}
__device__ __forceinline__ float fast_tanh(float x) {
    float ax = fabsf(x);
    float t = __expf(-2.f * ax);
    float r = (1.f - t) / (1.f + t);
    return copysignf(r, x);
}

// ---------------------------------------------------------------------------
// prep: transpose weights once per launch (same as round 0).
// ---------------------------------------------------------------------------
__global__ void prep_kernel(const float* __restrict__ msg_w1,
                            const float* __restrict__ msg_w2,
                            const float* __restrict__ gru_wih,
                            const float* __restrict__ gru_whh,
                            const float* __restrict__ head_w1,
                            float* __restrict__ msgW1T, float* __restrict__ msgW2T,
                            float* __restrict__ wihT, float* __restrict__ whhT,
                            float* __restrict__ headW1T) {
    int t = blockIdx.x * 256 + threadIdx.x;
    if (t < 3 * 8448) {  // msg W1T
        int l = t / 8448, r = t % 8448, k = r / 64, j = r % 64;
        msgW1T[t] = msg_w1[l * 8448 + j * 132 + k];
        return;
    }
    t -= 3 * 8448;
    if (t < 3 * 4096) {  // msg W2T
        int l = t / 4096, r = t % 4096, k = r / 64, j = r % 64;
        msgW2T[t] = msg_w2[l * 4096 + j * 64 + k];
        return;
    }
    t -= 3 * 4096;
    if (t < 3 * 12288) {  // wihT packed [l][g][kc][j][ks]
        int l = t / 12288, r = t % 12288;
        int ks = r & 3, j = (r >> 2) & 63, kcg = r >> 8;
        int kc = kcg & 15, g = kcg >> 4;
        wihT[t] = gru_wih[l * 12288 + (g * 64 + j) * 64 + kc * 4 + ks];
        return;
    }
    t -= 3 * 12288;
    if (t < 3 * 12288) {  // whhT packed
        int l = t / 12288, r = t % 12288;
        int ks = r & 3, j = (r >> 2) & 63, kcg = r >> 8;
        int kc = kcg & 15, g = kcg >> 4;
        whhT[t] = gru_whh[l * 12288 + (g * 64 + j) * 64 + kc * 4 + ks];
        return;
    }
    t -= 3 * 12288;
    if (t < 8448) {  // head W1T
        int k = t / 64, j = t % 64;
        headW1T[t] = head_w1[j * 132 + k];
    }
}

// h[n][d] = emb[kind[n]][d]
__global__ void embed_kernel(float* __restrict__ h, const float* __restrict__ emb,
                             const int* __restrict__ kinds, int N) {
    int t = blockIdx.x * 256 + threadIdx.x;
    if (t >= N * 16) return;
    int n = t >> 4, q = t & 15;
    ((float4*)h)[t] = ((const float4*)emb)[kinds[n] * 16 + q];
}

// -------------------- counting sort by dst --------------------
__global__ void hist_kernel(const int* __restrict__ dst, int* __restrict__ deg, int E) {
    int e = blockIdx.x * 256 + threadIdx.x;
    if (e < E) atomicAdd(&deg[dst[e]], 1);
}

// single-block exclusive scan of deg[N] -> cursor[N]
__global__ void scan_kernel(const int* __restrict__ deg, int* __restrict__ cursor, int N) {
    __shared__ int sums[1024];
    int tid = threadIdx.x;
    int chunk = (N + 1023) >> 10;
    int lo = tid * chunk, hi = min(lo + chunk, N);
    int s = 0;
    for (int i = lo; i < hi; i++) s += deg[i];
    sums[tid] = s;
    __syncthreads();
    for (int off = 1; off < 1024; off <<= 1) {
        int v = (tid >= off) ? sums[tid - off] : 0;
        __syncthreads();
        sums[tid] += v;
        __syncthreads();
    }
    int run = (tid > 0) ? sums[tid - 1] : 0;  // exclusive prefix
    for (int i = lo; i < hi; i++) {
        cursor[i] = run;
        run += deg[i];
    }
}

__global__ void scatter_kernel(const int* __restrict__ src, const int* __restrict__ dst,
                               const float* __restrict__ ea, int* __restrict__ cursor,
                               int* __restrict__ src_s, int* __restrict__ dst_s,
                               float* __restrict__ ea_s, int E) {
    int e = blockIdx.x * 256 + threadIdx.x;
    if (e >= E) return;
    int d = dst[e];
    int p = atomicAdd(&cursor[d], 1);
    src_s[p] = src[e];
    dst_s[p] = d;
    ((float4*)ea_s)[p] = ((const float4*)ea)[e];
}

// shared first-layer MLP: acc[j] = silu( sum_k W1T[k][j]*x[k] + b1[j] )
__device__ __forceinline__ void mlp132(const float4* __restrict__ hs4,
                                       const float4* __restrict__ hd4,
                                       float4 eattr,
                                       const float* __restrict__ W1T,
                                       const float* __restrict__ b1,
                                       float acc[64]) {
#pragma unroll
    for (int j = 0; j < 64; j++) acc[j] = b1[j];
#pragma unroll
    for (int c = 0; c < 16; c++) {
        float4 x = hs4[c];
        const float* w = W1T + c * 256;
#pragma unroll
        for (int j = 0; j < 64; j++)
            acc[j] += w[j] * x.x + w[64 + j] * x.y + w[128 + j] * x.z + w[192 + j] * x.w;
    }
#pragma unroll
    for (int c = 0; c < 16; c++) {
        float4 x = hd4[c];
        const float* w = W1T + 4096 + c * 256;
#pragma unroll
        for (int j = 0; j < 64; j++)
            acc[j] += w[j] * x.x + w[64 + j] * x.y + w[128 + j] * x.z + w[192 + j] * x.w;
    }
    {
        float4 x = eattr;
        const float* w = W1T + 8192;
#pragma unroll
        for (int j = 0; j < 64; j++)
            acc[j] += w[j] * x.x + w[64 + j] * x.y + w[128 + j] * x.z + w[192 + j] * x.w;
    }
#pragma unroll
    for (int j = 0; j < 64; j++) {
        float v = acc[j];
        acc[j] = v / (1.f + __expf(-v));  // silu
    }
}

// per-edge message (dst-sorted order) + wave-segmented reduction + tail atomics
__global__ __launch_bounds__(256) void edge_msg_kernel(
    const float* __restrict__ h, const int* __restrict__ src_s,
    const int* __restrict__ dst_s, const float* __restrict__ ea_s,
    const float* __restrict__ W1T, const float* __restrict__ b1,
    const float* __restrict__ W2T, const float* __restrict__ b2,
    float* __restrict__ agg, int E) {
    int t = blockIdx.x * 256 + threadIdx.x;
    int lane = threadIdx.x & 63;
    int tc = min(t, E - 1);  // clamp; fake lanes get unique dst and skip atomics

    int s = src_s[tc];
    int d = dst_s[tc];
    const float4* hs4 = (const float4*)(h + (size_t)s * 64);
    const float4* hd4 = (const float4*)(h + (size_t)d * 64);
    float4 eattr = ((const float4*)ea_s)[tc];

    float hid[64];
    mlp132(hs4, hd4, eattr, W1T, b1, hid);

    float m[64];
#pragma unroll
    for (int j = 0; j < 64; j++) m[j] = b2[j];
#pragma unroll
    for (int k = 0; k < 64; k++) {
        const float* w = W2T + k * 64;
        float xk = hid[k];
#pragma unroll
        for (int j = 0; j < 64; j++) m[j] += w[j] * xk;
    }

    // ---- wave-level segmented reduction over dst runs ----
    int dseg = (t < E) ? d : (-1 - lane);  // fake lanes: unique singleton segments
    int dprev = __shfl_up(dseg, 1);
    bool headf = (lane == 0) || (dprev != dseg);
    unsigned long long hb = __ballot(headf);
    unsigned long long mask_le = (~0ull) >> (63 - lane);
    int headlane = 63 - __builtin_clzll(hb & mask_le);
    int dist = lane - headlane;
    int dnext = __shfl_down(dseg, 1);
    bool tailf = (lane == 63) || (dnext != dseg);

#pragma unroll
    for (int st = 1; st < 64; st <<= 1) {
        bool ok = dist >= st;
#pragma unroll
        for (int j = 0; j < 64; j++) {
            float u = __shfl_up(m[j], st);
            m[j] = ok ? m[j] + u : m[j];
        }
    }

    if (tailf && t < E) {
        float* aggd = agg + (size_t)d * 64;
#pragma unroll
        for (int j = 0; j < 64; j++) unsafeAtomicAdd(aggd + j, m[j]);
    }
}

// GRU: 4 nodes per block; thread (node, j). agg/h rows staged in LDS.
__global__ __launch_bounds__(256) void gru_kernel(
    float* __restrict__ h, const float* __restrict__ agg,
    const float* __restrict__ wihT, const float* __restrict__ whhT,
    const float* __restrict__ bih, const float* __restrict__ bhh, int N) {
    int w = threadIdx.x >> 6, j = threadIdx.x & 63;
    int node = blockIdx.x * 4 + w;
    __shared__ float4 sa[4][16], sh[4][16];
    bool valid = node < N;
    if (valid && j < 16) sa[w][j] = ((const float4*)(agg + (size_t)node * 64))[j];
    if (valid && j >= 16 && j < 32) sh[w][j - 16] = ((const float4*)(h + (size_t)node * 64))[j - 16];
    __syncthreads();

    float accR = 0.f, accZ = 0.f, accI = 0.f, accH = 0.f;
    const float4* wi = (const float4*)wihT;
    const float4* wh = (const float4*)whhT;
#pragma unroll
    for (int kc = 0; kc < 16; kc++) {
        float4 a = sa[w][kc], hh = sh[w][kc];
        float4 t;
        t = wi[(0 * 16 + kc) * 64 + j]; accR += t.x * a.x + t.y * a.y + t.z * a.z + t.w * a.w;
        t = wh[(0 * 16 + kc) * 64 + j]; accR += t.x * hh.x + t.y * hh.y + t.z * hh.z + t.w * hh.w;
        t = wi[(1 * 16 + kc) * 64 + j]; accZ += t.x * a.x + t.y * a.y + t.z * a.z + t.w * a.w;
        t = wh[(1 * 16 + kc) * 64 + j]; accZ += t.x * hh.x + t.y * hh.y + t.z * hh.z + t.w * hh.w;
        t = wi[(2 * 16 + kc) * 64 + j]; accI += t.x * a.x + t.y * a.y + t.z * a.z + t.w * a.w;
        t = wh[(2 * 16 + kc) * 64 + j]; accH += t.x * hh.x + t.y * hh.y + t.z * hh.z + t.w * hh.w;
    }
    float r = fast_sig(accR + bih[j] + bhh[j]);
    float z = fast_sig(accZ + bih[64 + j] + bhh[64 + j]);
    float n = fast_tanh(accI + bih[128 + j] + r * (accH + bhh[128 + j]));
    if (valid) {
        float ho = ((const float*)&sh[w][0])[j];
        h[(size_t)node * 64 + j] = (1.f - z) * n + z * ho;
    }
}

// edge head (original edge order, coalesced)
__global__ __launch_bounds__(256) void head_kernel(
    const float* __restrict__ h, const int* __restrict__ src,
    const int* __restrict__ dst, const float* __restrict__ ea,
    const float* __restrict__ W1T, const float* __restrict__ b1,
    const float* __restrict__ hw2, const float* __restrict__ hb2,
    float* __restrict__ out, int E) {
    int e = blockIdx.x * 256 + threadIdx.x;
    if (e >= E) return;
    int s = src[e], d = dst[e];
    const float4* hs4 = (const float4*)(h + (size_t)s * 64);
    const float4* hd4 = (const float4*)(h + (size_t)d * 64);
    float4 eattr = ((const float4*)ea)[e];

    float hid[64];
    mlp132(hs4, hd4, eattr, W1T, b1, hid);

    float logit = hb2[0];
#pragma unroll
    for (int k = 0; k < 64; k++) logit += hw2[k] * hid[k];
    out[e] = fast_sig(logit);
}

extern "C" void kernel_launch(void* const* d_in, const int* in_sizes, int n_in,
                              void* d_out, int out_size, void* d_ws, size_t ws_size,
                              hipStream_t stream) {
    const int* edge_index = (const int*)d_in[0];
    int E = in_sizes[0] / 2;
    const int* src = edge_index;
    const int* dst = edge_index + E;
    const int* kinds = (const int*)d_in[1];
    int N = in_sizes[1];
    const float* edge_attr = (const float*)d_in[2];
    const float* emb = (const float*)d_in[3];
    const float* msg_w1 = (const float*)d_in[4];
    const float* msg_b1 = (const float*)d_in[5];
    const float* msg_w2 = (const float*)d_in[6];
    const float* msg_b2 = (const float*)d_in[7];
    const float* gru_wih = (const float*)d_in[8];
    const float* gru_whh = (const float*)d_in[9];
    const float* gru_bih = (const float*)d_in[10];
    const float* gru_bhh = (const float*)d_in[11];
    const float* head_w1 = (const float*)d_in[12];
    const float* head_b1 = (const float*)d_in[13];
    const float* head_w2 = (const float*)d_in[14];
    const float* head_b2 = (const float*)d_in[15];
    float* out = (float*)d_out;

    // workspace carve-up (floats / ints)
    float* ws = (float*)d_ws;
    float* h = ws;                            // N*64
    float* agg = h + (size_t)N * 64;          // N*64
    float* msgW1T = agg + (size_t)N * 64;     // 3*8448
    float* msgW2T = msgW1T + 3 * 8448;        // 3*4096
    float* wihT = msgW2T + 3 * 4096;          // 3*12288
    float* whhT = wihT + 3 * 12288;           // 3*12288
    float* headW1T = whhT + 3 * 12288;        // 8448
    float* ea_s = headW1T + 8448;             // E*4
    int* deg = (int*)(ea_s + (size_t)E * 4);  // N
    int* cursor = deg + N;                    // N
    int* src_s = cursor + N;                  // E
    int* dst_s = src_s + E;                   // E
    // total ≈ 46 MB

    prep_kernel<<<468, 256, 0, stream>>>(msg_w1, msg_w2, gru_wih, gru_whh, head_w1,
                                         msgW1T, msgW2T, wihT, whhT, headW1T);
    embed_kernel<<<(N * 16 + 255) / 256, 256, 0, stream>>>(h, emb, kinds, N);

    // counting sort by dst
    hipMemsetAsync(deg, 0, (size_t)N * sizeof(int), stream);
    hist_kernel<<<(E + 255) / 256, 256, 0, stream>>>(dst, deg, E);
    scan_kernel<<<1, 1024, 0, stream>>>(deg, cursor, N);
    scatter_kernel<<<(E + 255) / 256, 256, 0, stream>>>(src, dst, edge_attr, cursor,
                                                        src_s, dst_s, ea_s, E);

    for (int l = 0; l < 3; l++) {
        hipMemsetAsync(agg, 0, (size_t)N * 64 * sizeof(float), stream);
        edge_msg_kernel<<<(E + 255) / 256, 256, 0, stream>>>(
            h, src_s, dst_s, ea_s,
            msgW1T + l * 8448, msg_b1 + l * 64,
            msgW2T + l * 4096, msg_b2 + l * 64, agg, E);
        gru_kernel<<<(N + 3) / 4, 256, 0, stream>>>(
            h, agg, wihT + l * 12288, whhT + l * 12288,
            gru_bih + l * 192, gru_bhh + l * 192, N);
    }
    head_kernel<<<(E + 255) / 256, 256, 0, stream>>>(
        h, src, dst, edge_attr, headW1T, head_b1, head_w2, head_b2, out, E);
}

// Round 3
// 998.013 us; speedup vs baseline: 15.1309x; 11.0357x over previous
//
#include <hip/hip_runtime.h>
#include <hip/hip_bf16.h>

// ---------------------------------------------------------------------------
// HazardGNN round 3: edge message MLP + head as bf16 MFMA (16x16x32), fp32
// accumulate. Edges dst-sorted (counting sort). 128 edges/block, wave-private
// LDS slabs (no __syncthreads in the chunk loop). Aggregation: per-wave serial
// segment sum over sorted edges + tail fp32 atomics. GRU stays fp32.
// ---------------------------------------------------------------------------

typedef __attribute__((ext_vector_type(8))) short bf16x8;
typedef __attribute__((ext_vector_type(4))) float f32x4;
#define MFMA16(a, b, c) __builtin_amdgcn_mfma_f32_16x16x32_bf16(a, b, c, 0, 0, 0)

#define CHUNK 128
#define XSTRIDE 336   // bytes per x row: 168 bf16 (K padded to 160, +8 slack)
#define MSTRIDE 264   // bytes per m row: 66 f32
#define HSTRIDE 144   // bytes per hid row: 72 bf16
#define SLABSZ 10752  // 32 * XSTRIDE
#define HIDSZ  4608   // 32 * HSTRIDE

__device__ __forceinline__ float fast_sig(float x) { return 1.f / (1.f + __expf(-x)); }
__device__ __forceinline__ float fast_tanh(float x) {
    float ax = fabsf(x);
    float t = __expf(-2.f * ax);
    return copysignf((1.f - t) / (1.f + t), x);
}
__device__ __forceinline__ ushort f2bf(float f) {  // RNE fp32->bf16
    unsigned u = __float_as_uint(f);
    unsigned r = u + 0x7FFF + ((u >> 16) & 1);
    return (ushort)(r >> 16);
}

// ---------------------------------------------------------------------------
// prep: bf16 weight images for MFMA (row-major [out][K], K padded to 160 with
// zeros = B-operand layout directly) + fp32 packed GRU transposes.
// ---------------------------------------------------------------------------
__global__ void prep_kernel(const float* __restrict__ msg_w1,
                            const float* __restrict__ msg_w2,
                            const float* __restrict__ gru_wih,
                            const float* __restrict__ gru_whh,
                            const float* __restrict__ head_w1,
                            const float* __restrict__ head_w2,
                            ushort* __restrict__ Wb1, ushort* __restrict__ Wb2,
                            ushort* __restrict__ Wh1, ushort* __restrict__ Wh2b,
                            float* __restrict__ wihT, float* __restrict__ whhT) {
    int t = blockIdx.x * 256 + threadIdx.x;
    if (t < 30720) {  // Wb1[l][j][k<160]
        int l = t / 10240, r = t % 10240, j = r / 160, k = r % 160;
        Wb1[t] = (k < 132) ? f2bf(msg_w1[l * 8448 + j * 132 + k]) : 0;
        return;
    }
    t -= 30720;
    if (t < 12288) {  // Wb2[l][j][k<64] (same layout as input)
        Wb2[t] = f2bf(msg_w2[t]);
        return;
    }
    t -= 12288;
    if (t < 10240) {  // Wh1[j][k<160]
        int j = t / 160, k = t % 160;
        Wh1[t] = (k < 132) ? f2bf(head_w1[j * 132 + k]) : 0;
        return;
    }
    t -= 10240;
    if (t < 1024) {  // Wh2b[16][64]: row 0 = head_w2, rows 1..15 zero
        int j = t >> 6, k = t & 63;
        Wh2b[t] = (j == 0) ? f2bf(head_w2[k]) : 0;
        return;
    }
    t -= 1024;
    if (t < 36864) {  // wihT packed [l][g][kc][j][ks]
        int l = t / 12288, r = t % 12288;
        int ks = r & 3, j = (r >> 2) & 63, kcg = r >> 8;
        int kc = kcg & 15, g = kcg >> 4;
        wihT[t] = gru_wih[l * 12288 + (g * 64 + j) * 64 + kc * 4 + ks];
        return;
    }
    t -= 36864;
    if (t < 36864) {  // whhT packed
        int l = t / 12288, r = t % 12288;
        int ks = r & 3, j = (r >> 2) & 63, kcg = r >> 8;
        int kc = kcg & 15, g = kcg >> 4;
        whhT[t] = gru_whh[l * 12288 + (g * 64 + j) * 64 + kc * 4 + ks];
    }
}

// h (fp32) + hb (bf16 mirror) from embedding
__global__ void embed_kernel(float* __restrict__ h, ushort* __restrict__ hb,
                             const float* __restrict__ emb,
                             const int* __restrict__ kinds, int N) {
    int t = blockIdx.x * 256 + threadIdx.x;
    if (t >= N * 64) return;
    int node = t >> 6, d = t & 63;
    float v = emb[kinds[node] * 64 + d];
    h[t] = v;
    hb[t] = f2bf(v);
}

// -------------------- counting sort by dst --------------------
__global__ void hist_kernel(const int* __restrict__ dst, int* __restrict__ deg, int E) {
    int e = blockIdx.x * 256 + threadIdx.x;
    if (e < E) atomicAdd(&deg[dst[e]], 1);
}

__global__ void scan_kernel(const int* __restrict__ deg, int* __restrict__ cursor, int N) {
    __shared__ int sums[1024];
    int tid = threadIdx.x;
    int chunk = (N + 1023) >> 10;
    int lo = tid * chunk, hi = min(lo + chunk, N);
    int s = 0;
    for (int i = lo; i < hi; i++) s += deg[i];
    sums[tid] = s;
    __syncthreads();
    for (int off = 1; off < 1024; off <<= 1) {
        int v = (tid >= off) ? sums[tid - off] : 0;
        __syncthreads();
        sums[tid] += v;
        __syncthreads();
    }
    int run = (tid > 0) ? sums[tid - 1] : 0;
    for (int i = lo; i < hi; i++) {
        cursor[i] = run;
        run += deg[i];
    }
}

__global__ void scatter_kernel(const int* __restrict__ src, const int* __restrict__ dst,
                               const float* __restrict__ ea, int* __restrict__ cursor,
                               int* __restrict__ src_s, int* __restrict__ dst_s,
                               ushort* __restrict__ ea_sb, int E) {
    int e = blockIdx.x * 256 + threadIdx.x;
    if (e >= E) return;
    int d = dst[e];
    int p = atomicAdd(&cursor[d], 1);
    src_s[p] = src[e];
    dst_s[p] = d;
    float4 e4 = ((const float4*)ea)[e];
    ushort4 eb;
    eb.x = f2bf(e4.x); eb.y = f2bf(e4.y); eb.z = f2bf(e4.z); eb.w = f2bf(e4.w);
    ((ushort4*)ea_sb)[p] = eb;
}

// ---------------------------------------------------------------------------
// edge message MFMA kernel. 128 sorted edges per chunk, persistent blocks.
// Wave w owns rows [32w,32w+32): stages x, computes both GEMMs, aggregates.
// ---------------------------------------------------------------------------
__global__ __launch_bounds__(256) void edge_msg_mfma(
    const ushort* __restrict__ hb, const int* __restrict__ src_s,
    const int* __restrict__ dst_s, const ushort* __restrict__ ea_sb,
    const ushort* __restrict__ Wb1l, const ushort* __restrict__ Wb2l,
    const float* __restrict__ b1, const float* __restrict__ b2,
    float* __restrict__ agg, int E, int nchunks) {
    __shared__ char lds[4 * SLABSZ + 4 * HIDSZ];  // 61440 B
    int tid = threadIdx.x;
    int w = tid >> 6, lane = tid & 63;
    int quad = lane >> 4, nrow = lane & 15;
    char* slab = lds + w * SLABSZ;
    char* hidb = lds + 4 * SLABSZ + w * HIDSZ;

    // preload weight B-fragments + biases (per-dispatch constants)
    bf16x8 wf1[4][5], wf2[4][2];
    float b1v[4], b2v[4];
#pragma unroll
    for (int nt = 0; nt < 4; nt++) {
        int n = nt * 16 + nrow;
#pragma unroll
        for (int ks = 0; ks < 5; ks++)
            wf1[nt][ks] = *(const bf16x8*)(Wb1l + n * 160 + ks * 32 + quad * 8);
#pragma unroll
        for (int ks = 0; ks < 2; ks++)
            wf2[nt][ks] = *(const bf16x8*)(Wb2l + n * 64 + ks * 32 + quad * 8);
        b1v[nt] = b1[n];
        b2v[nt] = b2[n];
    }

    for (int chunk = blockIdx.x; chunk < nchunks; chunk += gridDim.x) {
        int ebase = chunk * CHUNK;
        // ---- stage x rows (wave-private; 2 threads per edge) ----
        {
            int el = tid >> 1, half = tid & 1;
            int r = el & 31;
            int ec = min(ebase + el, E - 1);
            int node = half ? dst_s[ec] : src_s[ec];
            const float4* hrow = (const float4*)(hb + (size_t)node * 64);
            float4* xw = (float4*)(slab + r * XSTRIDE + half * 128);
#pragma unroll
            for (int i = 0; i < 8; i++) xw[i] = hrow[i];
            if (half == 0) {  // edge attr -> cols 128..131
                *(uint2*)(slab + r * XSTRIDE + 256) = *(const uint2*)(ea_sb + (size_t)ec * 4);
            } else {  // zero pad cols 132..159
                uint2 z2 = {0u, 0u};
                float4 z4 = {0.f, 0.f, 0.f, 0.f};
                *(uint2*)(slab + r * XSTRIDE + 264) = z2;
                *(float4*)(slab + r * XSTRIDE + 272) = z4;
                *(float4*)(slab + r * XSTRIDE + 288) = z4;
                *(float4*)(slab + r * XSTRIDE + 304) = z4;
            }
        }
        // ---- layer 1: [32 x 160] @ [160 x 64] ----
        f32x4 acc1[2][4];
#pragma unroll
        for (int mt = 0; mt < 2; mt++)
#pragma unroll
            for (int nt = 0; nt < 4; nt++) {
                f32x4 v;
                v[0] = v[1] = v[2] = v[3] = b1v[nt];
                acc1[mt][nt] = v;
            }
#pragma unroll
        for (int ks = 0; ks < 5; ks++) {
            bf16x8 a0 = *(const bf16x8*)(slab + nrow * XSTRIDE + ks * 64 + quad * 16);
            bf16x8 a1 = *(const bf16x8*)(slab + (16 + nrow) * XSTRIDE + ks * 64 + quad * 16);
#pragma unroll
            for (int nt = 0; nt < 4; nt++) {
                acc1[0][nt] = MFMA16(a0, wf1[nt][ks], acc1[0][nt]);
                acc1[1][nt] = MFMA16(a1, wf1[nt][ks], acc1[1][nt]);
            }
        }
        // ---- SiLU -> hid (bf16, A-layout rows) ----
#pragma unroll
        for (int mt = 0; mt < 2; mt++)
#pragma unroll
            for (int nt = 0; nt < 4; nt++)
#pragma unroll
                for (int rg = 0; rg < 4; rg++) {
                    float v = acc1[mt][nt][rg];
                    v = v * fast_sig(v);
                    int rm = mt * 16 + quad * 4 + rg;
                    *(ushort*)(hidb + rm * HSTRIDE + (nt * 16 + nrow) * 2) = f2bf(v);
                }
        // ---- layer 2: [32 x 64] @ [64 x 64] ----
        f32x4 acc2[2][4];
#pragma unroll
        for (int mt = 0; mt < 2; mt++)
#pragma unroll
            for (int nt = 0; nt < 4; nt++) {
                f32x4 v;
                v[0] = v[1] = v[2] = v[3] = b2v[nt];
                acc2[mt][nt] = v;
            }
#pragma unroll
        for (int ks = 0; ks < 2; ks++) {
            bf16x8 a0 = *(const bf16x8*)(hidb + nrow * HSTRIDE + ks * 64 + quad * 16);
            bf16x8 a1 = *(const bf16x8*)(hidb + (16 + nrow) * HSTRIDE + ks * 64 + quad * 16);
#pragma unroll
            for (int nt = 0; nt < 4; nt++) {
                acc2[0][nt] = MFMA16(a0, wf2[nt][ks], acc2[0][nt]);
                acc2[1][nt] = MFMA16(a1, wf2[nt][ks], acc2[1][nt]);
            }
        }
        // ---- m -> slab (f32, aliases x region; wave-private so no barrier) ----
#pragma unroll
        for (int mt = 0; mt < 2; mt++)
#pragma unroll
            for (int nt = 0; nt < 4; nt++)
#pragma unroll
                for (int rg = 0; rg < 4; rg++) {
                    int rm = mt * 16 + quad * 4 + rg;
                    *(float*)(slab + rm * MSTRIDE + (nt * 16 + nrow) * 4) = acc2[mt][nt][rg];
                }
        // ---- segmented aggregation over this wave's 32 sorted edges ----
        {
            int e32 = ebase + w * 32;
            int dmy = dst_s[min(e32 + (lane & 31), E - 1)];
            int limit = min(32, E - e32);
            int nx = __shfl_down(dmy, 1);
            bool tl = ((lane & 31) == 31) || (dmy != nx);
            unsigned long long tm = __ballot(tl);
            float run = 0.f;
#pragma unroll
            for (int i = 0; i < 32; i++) {
                if (i < limit) {
                    run += *(const float*)(slab + i * MSTRIDE + lane * 4);
                    if (((tm >> i) & 1ull) || (i + 1 == limit)) {
                        int di = __shfl(dmy, i);
                        unsafeAtomicAdd(&agg[(size_t)di * 64 + lane], run);
                        run = 0.f;
                    }
                }
            }
        }
    }
}

// ---------------------------------------------------------------------------
// head MFMA kernel: layer1 same shape; layer2 = dot with head_w2 via N=16 MFMA
// (B rows 1..15 zero). Original edge order.
// ---------------------------------------------------------------------------
__global__ __launch_bounds__(256) void head_mfma(
    const ushort* __restrict__ hb, const int* __restrict__ src,
    const int* __restrict__ dst, const float* __restrict__ ea,
    const ushort* __restrict__ Wh1, const ushort* __restrict__ Wh2b,
    const float* __restrict__ hb1, const float* __restrict__ hb2p,
    float* __restrict__ out, int E, int nchunks) {
    __shared__ char lds[4 * SLABSZ + 4 * HIDSZ];
    int tid = threadIdx.x;
    int w = tid >> 6, lane = tid & 63;
    int quad = lane >> 4, nrow = lane & 15;
    char* slab = lds + w * SLABSZ;
    char* hidb = lds + 4 * SLABSZ + w * HIDSZ;

    bf16x8 wf1[4][5], wh2[2];
    float b1v[4];
#pragma unroll
    for (int nt = 0; nt < 4; nt++) {
        int n = nt * 16 + nrow;
#pragma unroll
        for (int ks = 0; ks < 5; ks++)
            wf1[nt][ks] = *(const bf16x8*)(Wh1 + n * 160 + ks * 32 + quad * 8);
        b1v[nt] = hb1[n];
    }
#pragma unroll
    for (int ks = 0; ks < 2; ks++)
        wh2[ks] = *(const bf16x8*)(Wh2b + nrow * 64 + ks * 32 + quad * 8);
    float hb2 = hb2p[0];

    for (int chunk = blockIdx.x; chunk < nchunks; chunk += gridDim.x) {
        int ebase = chunk * CHUNK;
        {
            int el = tid >> 1, half = tid & 1;
            int r = el & 31;
            int ec = min(ebase + el, E - 1);
            int node = half ? dst[ec] : src[ec];
            const float4* hrow = (const float4*)(hb + (size_t)node * 64);
            float4* xw = (float4*)(slab + r * XSTRIDE + half * 128);
#pragma unroll
            for (int i = 0; i < 8; i++) xw[i] = hrow[i];
            if (half == 0) {
                float4 e4 = ((const float4*)ea)[ec];
                ushort4 eb;
                eb.x = f2bf(e4.x); eb.y = f2bf(e4.y); eb.z = f2bf(e4.z); eb.w = f2bf(e4.w);
                *(ushort4*)(slab + r * XSTRIDE + 256) = eb;
            } else {
                uint2 z2 = {0u, 0u};
                float4 z4 = {0.f, 0.f, 0.f, 0.f};
                *(uint2*)(slab + r * XSTRIDE + 264) = z2;
                *(float4*)(slab + r * XSTRIDE + 272) = z4;
                *(float4*)(slab + r * XSTRIDE + 288) = z4;
                *(float4*)(slab + r * XSTRIDE + 304) = z4;
            }
        }
        f32x4 acc1[2][4];
#pragma unroll
        for (int mt = 0; mt < 2; mt++)
#pragma unroll
            for (int nt = 0; nt < 4; nt++) {
                f32x4 v;
                v[0] = v[1] = v[2] = v[3] = b1v[nt];
                acc1[mt][nt] = v;
            }
#pragma unroll
        for (int ks = 0; ks < 5; ks++) {
            bf16x8 a0 = *(const bf16x8*)(slab + nrow * XSTRIDE + ks * 64 + quad * 16);
            bf16x8 a1 = *(const bf16x8*)(slab + (16 + nrow) * XSTRIDE + ks * 64 + quad * 16);
#pragma unroll
            for (int nt = 0; nt < 4; nt++) {
                acc1[0][nt] = MFMA16(a0, wf1[nt][ks], acc1[0][nt]);
                acc1[1][nt] = MFMA16(a1, wf1[nt][ks], acc1[1][nt]);
            }
        }
#pragma unroll
        for (int mt = 0; mt < 2; mt++)
#pragma unroll
            for (int nt = 0; nt < 4; nt++)
#pragma unroll
                for (int rg = 0; rg < 4; rg++) {
                    float v = acc1[mt][nt][rg];
                    v = v * fast_sig(v);
                    int rm = mt * 16 + quad * 4 + rg;
                    *(ushort*)(hidb + rm * HSTRIDE + (nt * 16 + nrow) * 2) = f2bf(v);
                }
        f32x4 acc3[2];
#pragma unroll
        for (int mt = 0; mt < 2; mt++) {
            f32x4 v;
            v[0] = v[1] = v[2] = v[3] = 0.f;
            acc3[mt] = v;
        }
#pragma unroll
        for (int ks = 0; ks < 2; ks++) {
            bf16x8 a0 = *(const bf16x8*)(hidb + nrow * HSTRIDE + ks * 64 + quad * 16);
            bf16x8 a1 = *(const bf16x8*)(hidb + (16 + nrow) * HSTRIDE + ks * 64 + quad * 16);
            acc3[0] = MFMA16(a0, wh2[ks], acc3[0]);
            acc3[1] = MFMA16(a1, wh2[ks], acc3[1]);
        }
        if (nrow == 0) {  // col 0 holds the logits
#pragma unroll
            for (int mt = 0; mt < 2; mt++)
#pragma unroll
                for (int rg = 0; rg < 4; rg++) {
                    int e = ebase + w * 32 + mt * 16 + quad * 4 + rg;
                    if (e < E) out[e] = fast_sig(acc3[mt][rg] + hb2);
                }
        }
    }
}

// GRU: 4 nodes per block (unchanged math) + bf16 mirror write
__global__ __launch_bounds__(256) void gru_kernel(
    float* __restrict__ h, ushort* __restrict__ hbm, const float* __restrict__ agg,
    const float* __restrict__ wihT, const float* __restrict__ whhT,
    const float* __restrict__ bih, const float* __restrict__ bhh, int N) {
    int w = threadIdx.x >> 6, j = threadIdx.x & 63;
    int node = blockIdx.x * 4 + w;
    __shared__ float4 sa[4][16], sh[4][16];
    bool valid = node < N;
    if (valid && j < 16) sa[w][j] = ((const float4*)(agg + (size_t)node * 64))[j];
    if (valid && j >= 16 && j < 32) sh[w][j - 16] = ((const float4*)(h + (size_t)node * 64))[j - 16];
    __syncthreads();

    float accR = 0.f, accZ = 0.f, accI = 0.f, accH = 0.f;
    const float4* wi = (const float4*)wihT;
    const float4* wh = (const float4*)whhT;
#pragma unroll
    for (int kc = 0; kc < 16; kc++) {
        float4 a = sa[w][kc], hh = sh[w][kc];
        float4 t;
        t = wi[(0 * 16 + kc) * 64 + j]; accR += t.x * a.x + t.y * a.y + t.z * a.z + t.w * a.w;
        t = wh[(0 * 16 + kc) * 64 + j]; accR += t.x * hh.x + t.y * hh.y + t.z * hh.z + t.w * hh.w;
        t = wi[(1 * 16 + kc) * 64 + j]; accZ += t.x * a.x + t.y * a.y + t.z * a.z + t.w * a.w;
        t = wh[(1 * 16 + kc) * 64 + j]; accZ += t.x * hh.x + t.y * hh.y + t.z * hh.z + t.w * hh.w;
        t = wi[(2 * 16 + kc) * 64 + j]; accI += t.x * a.x + t.y * a.y + t.z * a.z + t.w * a.w;
        t = wh[(2 * 16 + kc) * 64 + j]; accH += t.x * hh.x + t.y * hh.y + t.z * hh.z + t.w * hh.w;
    }
    float r = fast_sig(accR + bih[j] + bhh[j]);
    float z = fast_sig(accZ + bih[64 + j] + bhh[64 + j]);
    float n = fast_tanh(accI + bih[128 + j] + r * (accH + bhh[128 + j]));
    if (valid) {
        float ho = ((const float*)&sh[w][0])[j];
        float hn = (1.f - z) * n + z * ho;
        h[(size_t)node * 64 + j] = hn;
        hbm[(size_t)node * 64 + j] = f2bf(hn);
    }
}

extern "C" void kernel_launch(void* const* d_in, const int* in_sizes, int n_in,
                              void* d_out, int out_size, void* d_ws, size_t ws_size,
                              hipStream_t stream) {
    const int* edge_index = (const int*)d_in[0];
    int E = in_sizes[0] / 2;
    const int* src = edge_index;
    const int* dst = edge_index + E;
    const int* kinds = (const int*)d_in[1];
    int N = in_sizes[1];
    const float* edge_attr = (const float*)d_in[2];
    const float* emb = (const float*)d_in[3];
    const float* msg_w1 = (const float*)d_in[4];
    const float* msg_b1 = (const float*)d_in[5];
    const float* msg_w2 = (const float*)d_in[6];
    const float* msg_b2 = (const float*)d_in[7];
    const float* gru_wih = (const float*)d_in[8];
    const float* gru_whh = (const float*)d_in[9];
    const float* gru_bih = (const float*)d_in[10];
    const float* gru_bhh = (const float*)d_in[11];
    const float* head_w1 = (const float*)d_in[12];
    const float* head_b1 = (const float*)d_in[13];
    const float* head_w2 = (const float*)d_in[14];
    const float* head_b2 = (const float*)d_in[15];
    float* out = (float*)d_out;

    // workspace carve-up
    char* p = (char*)d_ws;
    float* h = (float*)p;        p += (size_t)N * 64 * 4;
    float* agg = (float*)p;      p += (size_t)N * 64 * 4;
    float* wihT = (float*)p;     p += 36864 * 4;
    float* whhT = (float*)p;     p += 36864 * 4;
    int* deg = (int*)p;          p += (size_t)N * 4;
    int* cursor = (int*)p;       p += (size_t)N * 4;
    int* src_s = (int*)p;        p += (size_t)E * 4;
    int* dst_s = (int*)p;        p += (size_t)E * 4;
    ushort* hb = (ushort*)p;     p += (size_t)N * 64 * 2;
    ushort* Wb1 = (ushort*)p;    p += 30720 * 2;
    ushort* Wb2 = (ushort*)p;    p += 12288 * 2;
    ushort* Wh1 = (ushort*)p;    p += 10240 * 2;
    ushort* Wh2b = (ushort*)p;   p += 1024 * 2;
    ushort* ea_sb = (ushort*)p;  p += (size_t)E * 4 * 2;

    int nchunks = (E + CHUNK - 1) / CHUNK;

    prep_kernel<<<500, 256, 0, stream>>>(msg_w1, msg_w2, gru_wih, gru_whh, head_w1,
                                         head_w2, Wb1, Wb2, Wh1, Wh2b, wihT, whhT);
    embed_kernel<<<(N * 64 + 255) / 256, 256, 0, stream>>>(h, hb, emb, kinds, N);

    hipMemsetAsync(deg, 0, (size_t)N * sizeof(int), stream);
    hist_kernel<<<(E + 255) / 256, 256, 0, stream>>>(dst, deg, E);
    scan_kernel<<<1, 1024, 0, stream>>>(deg, cursor, N);
    scatter_kernel<<<(E + 255) / 256, 256, 0, stream>>>(src, dst, edge_attr, cursor,
                                                        src_s, dst_s, ea_sb, E);

    for (int l = 0; l < 3; l++) {
        hipMemsetAsync(agg, 0, (size_t)N * 64 * sizeof(float), stream);
        edge_msg_mfma<<<512, 256, 0, stream>>>(
            hb, src_s, dst_s, ea_sb,
            Wb1 + l * 10240, Wb2 + l * 4096,
            msg_b1 + l * 64, msg_b2 + l * 64, agg, E, nchunks);
        gru_kernel<<<(N + 3) / 4, 256, 0, stream>>>(
            h, hb, agg, wihT + l * 12288, whhT + l * 12288,
            gru_bih + l * 192, gru_bhh + l * 192, N);
    }
    head_mfma<<<512, 256, 0, stream>>>(hb, src, dst, edge_attr, Wh1, Wh2b,
                                       head_b1, head_b2, out, E, nchunks);
}

// Round 4
// 685.859 us; speedup vs baseline: 22.0175x; 1.4551x over previous
//
#include <hip/hip_runtime.h>
#include <hip/hip_bf16.h>

// ---------------------------------------------------------------------------
// HazardGNN round 4: GRU moves to bf16 MFMA (stacked-K trick for r,z gates;
// separate inn/hn accumulators; elementwise gate math in C-layout registers).
// Edge message / head MFMA kernels unchanged from round 3.
// ---------------------------------------------------------------------------

typedef __attribute__((ext_vector_type(8))) short bf16x8;
typedef __attribute__((ext_vector_type(4))) float f32x4;
#define MFMA16(a, b, c) __builtin_amdgcn_mfma_f32_16x16x32_bf16(a, b, c, 0, 0, 0)

#define CHUNK 128
#define XSTRIDE 336   // bytes per x row: 168 bf16 (K padded to 160, +8 slack)
#define MSTRIDE 264   // bytes per m row: 66 f32
#define HSTRIDE 144   // bytes per hid row: 72 bf16
#define SLABSZ 10752  // 32 * XSTRIDE
#define HIDSZ  4608   // 32 * HSTRIDE

// GRU LDS strides (+8 bf16 pad to break power-of-2 banking)
#define WRZST 264     // 128 bf16 + 4 pad
#define WNST  136     // 64 bf16 + 4 pad

__device__ __forceinline__ float fast_sig(float x) { return 1.f / (1.f + __expf(-x)); }
__device__ __forceinline__ float fast_tanh(float x) {
    float ax = fabsf(x);
    float t = __expf(-2.f * ax);
    return copysignf((1.f - t) / (1.f + t), x);
}
__device__ __forceinline__ ushort f2bf(float f) {  // RNE fp32->bf16
    unsigned u = __float_as_uint(f);
    unsigned r = u + 0x7FFF + ((u >> 16) & 1);
    return (ushort)(r >> 16);
}

// ---------------------------------------------------------------------------
// prep: bf16 weight images. Msg/head as before; GRU weights stacked:
//  Wrz[l][n<128][k<128] : k<64 -> wih[n][k], k>=64 -> whh[n][k-64]
//  Wni[l][j<64][k<64]   : wih[128+j][k]
//  Wnh[l][j<64][k<64]   : whh[128+j][k]
// ---------------------------------------------------------------------------
__global__ void prep_kernel(const float* __restrict__ msg_w1,
                            const float* __restrict__ msg_w2,
                            const float* __restrict__ gru_wih,
                            const float* __restrict__ gru_whh,
                            const float* __restrict__ head_w1,
                            const float* __restrict__ head_w2,
                            ushort* __restrict__ Wb1, ushort* __restrict__ Wb2,
                            ushort* __restrict__ Wh1, ushort* __restrict__ Wh2b,
                            ushort* __restrict__ Wrz, ushort* __restrict__ Wni,
                            ushort* __restrict__ Wnh) {
    int t = blockIdx.x * 256 + threadIdx.x;
    if (t < 30720) {  // Wb1[l][j][k<160]
        int l = t / 10240, r = t % 10240, j = r / 160, k = r % 160;
        Wb1[t] = (k < 132) ? f2bf(msg_w1[l * 8448 + j * 132 + k]) : 0;
        return;
    }
    t -= 30720;
    if (t < 12288) {  // Wb2[l][j][k<64]
        Wb2[t] = f2bf(msg_w2[t]);
        return;
    }
    t -= 12288;
    if (t < 10240) {  // Wh1[j][k<160]
        int j = t / 160, k = t % 160;
        Wh1[t] = (k < 132) ? f2bf(head_w1[j * 132 + k]) : 0;
        return;
    }
    t -= 10240;
    if (t < 1024) {  // Wh2b[16][64]: row 0 = head_w2, rows 1..15 zero
        int j = t >> 6, k = t & 63;
        Wh2b[t] = (j == 0) ? f2bf(head_w2[k]) : 0;
        return;
    }
    t -= 1024;
    if (t < 49152) {  // Wrz[l][n][k]
        int l = t / 16384, r = t % 16384, n = r >> 7, k = r & 127;
        float v = (k < 64) ? gru_wih[l * 12288 + n * 64 + k]
                           : gru_whh[l * 12288 + n * 64 + (k - 64)];
        Wrz[t] = f2bf(v);
        return;
    }
    t -= 49152;
    if (t < 12288) {  // Wni[l][j][k]
        int l = t / 4096, r = t % 4096, j = r >> 6, k = r & 63;
        Wni[t] = f2bf(gru_wih[l * 12288 + (128 + j) * 64 + k]);
        return;
    }
    t -= 12288;
    if (t < 12288) {  // Wnh[l][j][k]
        int l = t / 4096, r = t % 4096, j = r >> 6, k = r & 63;
        Wnh[t] = f2bf(gru_whh[l * 12288 + (128 + j) * 64 + k]);
    }
}

// h (fp32) + hb (bf16 mirror) from embedding
__global__ void embed_kernel(float* __restrict__ h, ushort* __restrict__ hb,
                             const float* __restrict__ emb,
                             const int* __restrict__ kinds, int N) {
    int t = blockIdx.x * 256 + threadIdx.x;
    if (t >= N * 64) return;
    int node = t >> 6, d = t & 63;
    float v = emb[kinds[node] * 64 + d];
    h[t] = v;
    hb[t] = f2bf(v);
}

// -------------------- counting sort by dst --------------------
__global__ void hist_kernel(const int* __restrict__ dst, int* __restrict__ deg, int E) {
    int e = blockIdx.x * 256 + threadIdx.x;
    if (e < E) atomicAdd(&deg[dst[e]], 1);
}

__global__ void scan_kernel(const int* __restrict__ deg, int* __restrict__ cursor, int N) {
    __shared__ int sums[1024];
    int tid = threadIdx.x;
    int chunk = (N + 1023) >> 10;
    int lo = tid * chunk, hi = min(lo + chunk, N);
    int s = 0;
    for (int i = lo; i < hi; i++) s += deg[i];
    sums[tid] = s;
    __syncthreads();
    for (int off = 1; off < 1024; off <<= 1) {
        int v = (tid >= off) ? sums[tid - off] : 0;
        __syncthreads();
        sums[tid] += v;
        __syncthreads();
    }
    int run = (tid > 0) ? sums[tid - 1] : 0;
    for (int i = lo; i < hi; i++) {
        cursor[i] = run;
        run += deg[i];
    }
}

__global__ void scatter_kernel(const int* __restrict__ src, const int* __restrict__ dst,
                               const float* __restrict__ ea, int* __restrict__ cursor,
                               int* __restrict__ src_s, int* __restrict__ dst_s,
                               ushort* __restrict__ ea_sb, int E) {
    int e = blockIdx.x * 256 + threadIdx.x;
    if (e >= E) return;
    int d = dst[e];
    int p = atomicAdd(&cursor[d], 1);
    src_s[p] = src[e];
    dst_s[p] = d;
    float4 e4 = ((const float4*)ea)[e];
    ushort4 eb;
    eb.x = f2bf(e4.x); eb.y = f2bf(e4.y); eb.z = f2bf(e4.z); eb.w = f2bf(e4.w);
    ((ushort4*)ea_sb)[p] = eb;
}

// ---------------------------------------------------------------------------
// edge message MFMA kernel (unchanged from round 3).
// ---------------------------------------------------------------------------
__global__ __launch_bounds__(256) void edge_msg_mfma(
    const ushort* __restrict__ hb, const int* __restrict__ src_s,
    const int* __restrict__ dst_s, const ushort* __restrict__ ea_sb,
    const ushort* __restrict__ Wb1l, const ushort* __restrict__ Wb2l,
    const float* __restrict__ b1, const float* __restrict__ b2,
    float* __restrict__ agg, int E, int nchunks) {
    __shared__ char lds[4 * SLABSZ + 4 * HIDSZ];  // 61440 B
    int tid = threadIdx.x;
    int w = tid >> 6, lane = tid & 63;
    int quad = lane >> 4, nrow = lane & 15;
    char* slab = lds + w * SLABSZ;
    char* hidb = lds + 4 * SLABSZ + w * HIDSZ;

    bf16x8 wf1[4][5], wf2[4][2];
    float b1v[4], b2v[4];
#pragma unroll
    for (int nt = 0; nt < 4; nt++) {
        int n = nt * 16 + nrow;
#pragma unroll
        for (int ks = 0; ks < 5; ks++)
            wf1[nt][ks] = *(const bf16x8*)(Wb1l + n * 160 + ks * 32 + quad * 8);
#pragma unroll
        for (int ks = 0; ks < 2; ks++)
            wf2[nt][ks] = *(const bf16x8*)(Wb2l + n * 64 + ks * 32 + quad * 8);
        b1v[nt] = b1[n];
        b2v[nt] = b2[n];
    }

    for (int chunk = blockIdx.x; chunk < nchunks; chunk += gridDim.x) {
        int ebase = chunk * CHUNK;
        {
            int el = tid >> 1, half = tid & 1;
            int r = el & 31;
            int ec = min(ebase + el, E - 1);
            int node = half ? dst_s[ec] : src_s[ec];
            const float4* hrow = (const float4*)(hb + (size_t)node * 64);
            float4* xw = (float4*)(slab + r * XSTRIDE + half * 128);
#pragma unroll
            for (int i = 0; i < 8; i++) xw[i] = hrow[i];
            if (half == 0) {
                *(uint2*)(slab + r * XSTRIDE + 256) = *(const uint2*)(ea_sb + (size_t)ec * 4);
            } else {
                uint2 z2 = {0u, 0u};
                float4 z4 = {0.f, 0.f, 0.f, 0.f};
                *(uint2*)(slab + r * XSTRIDE + 264) = z2;
                *(float4*)(slab + r * XSTRIDE + 272) = z4;
                *(float4*)(slab + r * XSTRIDE + 288) = z4;
                *(float4*)(slab + r * XSTRIDE + 304) = z4;
            }
        }
        f32x4 acc1[2][4];
#pragma unroll
        for (int mt = 0; mt < 2; mt++)
#pragma unroll
            for (int nt = 0; nt < 4; nt++) {
                f32x4 v;
                v[0] = v[1] = v[2] = v[3] = b1v[nt];
                acc1[mt][nt] = v;
            }
#pragma unroll
        for (int ks = 0; ks < 5; ks++) {
            bf16x8 a0 = *(const bf16x8*)(slab + nrow * XSTRIDE + ks * 64 + quad * 16);
            bf16x8 a1 = *(const bf16x8*)(slab + (16 + nrow) * XSTRIDE + ks * 64 + quad * 16);
#pragma unroll
            for (int nt = 0; nt < 4; nt++) {
                acc1[0][nt] = MFMA16(a0, wf1[nt][ks], acc1[0][nt]);
                acc1[1][nt] = MFMA16(a1, wf1[nt][ks], acc1[1][nt]);
            }
        }
#pragma unroll
        for (int mt = 0; mt < 2; mt++)
#pragma unroll
            for (int nt = 0; nt < 4; nt++)
#pragma unroll
                for (int rg = 0; rg < 4; rg++) {
                    float v = acc1[mt][nt][rg];
                    v = v * fast_sig(v);
                    int rm = mt * 16 + quad * 4 + rg;
                    *(ushort*)(hidb + rm * HSTRIDE + (nt * 16 + nrow) * 2) = f2bf(v);
                }
        f32x4 acc2[2][4];
#pragma unroll
        for (int mt = 0; mt < 2; mt++)
#pragma unroll
            for (int nt = 0; nt < 4; nt++) {
                f32x4 v;
                v[0] = v[1] = v[2] = v[3] = b2v[nt];
                acc2[mt][nt] = v;
            }
#pragma unroll
        for (int ks = 0; ks < 2; ks++) {
            bf16x8 a0 = *(const bf16x8*)(hidb + nrow * HSTRIDE + ks * 64 + quad * 16);
            bf16x8 a1 = *(const bf16x8*)(hidb + (16 + nrow) * HSTRIDE + ks * 64 + quad * 16);
#pragma unroll
            for (int nt = 0; nt < 4; nt++) {
                acc2[0][nt] = MFMA16(a0, wf2[nt][ks], acc2[0][nt]);
                acc2[1][nt] = MFMA16(a1, wf2[nt][ks], acc2[1][nt]);
            }
        }
#pragma unroll
        for (int mt = 0; mt < 2; mt++)
#pragma unroll
            for (int nt = 0; nt < 4; nt++)
#pragma unroll
                for (int rg = 0; rg < 4; rg++) {
                    int rm = mt * 16 + quad * 4 + rg;
                    *(float*)(slab + rm * MSTRIDE + (nt * 16 + nrow) * 4) = acc2[mt][nt][rg];
                }
        {
            int e32 = ebase + w * 32;
            int dmy = dst_s[min(e32 + (lane & 31), E - 1)];
            int limit = min(32, E - e32);
            int nx = __shfl_down(dmy, 1);
            bool tl = ((lane & 31) == 31) || (dmy != nx);
            unsigned long long tm = __ballot(tl);
            float run = 0.f;
#pragma unroll
            for (int i = 0; i < 32; i++) {
                if (i < limit) {
                    run += *(const float*)(slab + i * MSTRIDE + lane * 4);
                    if (((tm >> i) & 1ull) || (i + 1 == limit)) {
                        int di = __shfl(dmy, i);
                        unsafeAtomicAdd(&agg[(size_t)di * 64 + lane], run);
                        run = 0.f;
                    }
                }
            }
        }
    }
}

// ---------------------------------------------------------------------------
// head MFMA kernel (unchanged from round 3).
// ---------------------------------------------------------------------------
__global__ __launch_bounds__(256) void head_mfma(
    const ushort* __restrict__ hb, const int* __restrict__ src,
    const int* __restrict__ dst, const float* __restrict__ ea,
    const ushort* __restrict__ Wh1, const ushort* __restrict__ Wh2b,
    const float* __restrict__ hb1, const float* __restrict__ hb2p,
    float* __restrict__ out, int E, int nchunks) {
    __shared__ char lds[4 * SLABSZ + 4 * HIDSZ];
    int tid = threadIdx.x;
    int w = tid >> 6, lane = tid & 63;
    int quad = lane >> 4, nrow = lane & 15;
    char* slab = lds + w * SLABSZ;
    char* hidb = lds + 4 * SLABSZ + w * HIDSZ;

    bf16x8 wf1[4][5], wh2[2];
    float b1v[4];
#pragma unroll
    for (int nt = 0; nt < 4; nt++) {
        int n = nt * 16 + nrow;
#pragma unroll
        for (int ks = 0; ks < 5; ks++)
            wf1[nt][ks] = *(const bf16x8*)(Wh1 + n * 160 + ks * 32 + quad * 8);
        b1v[nt] = hb1[n];
    }
#pragma unroll
    for (int ks = 0; ks < 2; ks++)
        wh2[ks] = *(const bf16x8*)(Wh2b + nrow * 64 + ks * 32 + quad * 8);
    float hb2 = hb2p[0];

    for (int chunk = blockIdx.x; chunk < nchunks; chunk += gridDim.x) {
        int ebase = chunk * CHUNK;
        {
            int el = tid >> 1, half = tid & 1;
            int r = el & 31;
            int ec = min(ebase + el, E - 1);
            int node = half ? dst[ec] : src[ec];
            const float4* hrow = (const float4*)(hb + (size_t)node * 64);
            float4* xw = (float4*)(slab + r * XSTRIDE + half * 128);
#pragma unroll
            for (int i = 0; i < 8; i++) xw[i] = hrow[i];
            if (half == 0) {
                float4 e4 = ((const float4*)ea)[ec];
                ushort4 eb;
                eb.x = f2bf(e4.x); eb.y = f2bf(e4.y); eb.z = f2bf(e4.z); eb.w = f2bf(e4.w);
                *(ushort4*)(slab + r * XSTRIDE + 256) = eb;
            } else {
                uint2 z2 = {0u, 0u};
                float4 z4 = {0.f, 0.f, 0.f, 0.f};
                *(uint2*)(slab + r * XSTRIDE + 264) = z2;
                *(float4*)(slab + r * XSTRIDE + 272) = z4;
                *(float4*)(slab + r * XSTRIDE + 288) = z4;
                *(float4*)(slab + r * XSTRIDE + 304) = z4;
            }
        }
        f32x4 acc1[2][4];
#pragma unroll
        for (int mt = 0; mt < 2; mt++)
#pragma unroll
            for (int nt = 0; nt < 4; nt++) {
                f32x4 v;
                v[0] = v[1] = v[2] = v[3] = b1v[nt];
                acc1[mt][nt] = v;
            }
#pragma unroll
        for (int ks = 0; ks < 5; ks++) {
            bf16x8 a0 = *(const bf16x8*)(slab + nrow * XSTRIDE + ks * 64 + quad * 16);
            bf16x8 a1 = *(const bf16x8*)(slab + (16 + nrow) * XSTRIDE + ks * 64 + quad * 16);
#pragma unroll
            for (int nt = 0; nt < 4; nt++) {
                acc1[0][nt] = MFMA16(a0, wf1[nt][ks], acc1[0][nt]);
                acc1[1][nt] = MFMA16(a1, wf1[nt][ks], acc1[1][nt]);
            }
        }
#pragma unroll
        for (int mt = 0; mt < 2; mt++)
#pragma unroll
            for (int nt = 0; nt < 4; nt++)
#pragma unroll
                for (int rg = 0; rg < 4; rg++) {
                    float v = acc1[mt][nt][rg];
                    v = v * fast_sig(v);
                    int rm = mt * 16 + quad * 4 + rg;
                    *(ushort*)(hidb + rm * HSTRIDE + (nt * 16 + nrow) * 2) = f2bf(v);
                }
        f32x4 acc3[2];
#pragma unroll
        for (int mt = 0; mt < 2; mt++) {
            f32x4 v;
            v[0] = v[1] = v[2] = v[3] = 0.f;
            acc3[mt] = v;
        }
#pragma unroll
        for (int ks = 0; ks < 2; ks++) {
            bf16x8 a0 = *(const bf16x8*)(hidb + nrow * HSTRIDE + ks * 64 + quad * 16);
            bf16x8 a1 = *(const bf16x8*)(hidb + (16 + nrow) * HSTRIDE + ks * 64 + quad * 16);
            acc3[0] = MFMA16(a0, wh2[ks], acc3[0]);
            acc3[1] = MFMA16(a1, wh2[ks], acc3[1]);
        }
        if (nrow == 0) {
#pragma unroll
            for (int mt = 0; mt < 2; mt++)
#pragma unroll
                for (int rg = 0; rg < 4; rg++) {
                    int e = ebase + w * 32 + mt * 16 + quad * 4 + rg;
                    if (e < E) out[e] = fast_sig(acc3[mt][rg] + hb2);
                }
        }
    }
}

// ---------------------------------------------------------------------------
// GRU MFMA kernel. 128 nodes/block, 32/wave. Stacked-K (agg|h, K=128) for r,z;
// separate inn (A=agg) / hn (A=h) accumulators. A-frags built directly from
// global (agg fp32->bf16 on the fly; hb already bf16). Weights in LDS.
// ---------------------------------------------------------------------------
__device__ __forceinline__ bf16x8 aggfrag(const float* __restrict__ row, int off) {
    float4 f0 = *(const float4*)(row + off);
    float4 f1 = *(const float4*)(row + off + 4);
    bf16x8 r;
    r[0] = (short)f2bf(f0.x); r[1] = (short)f2bf(f0.y);
    r[2] = (short)f2bf(f0.z); r[3] = (short)f2bf(f0.w);
    r[4] = (short)f2bf(f1.x); r[5] = (short)f2bf(f1.y);
    r[6] = (short)f2bf(f1.z); r[7] = (short)f2bf(f1.w);
    return r;
}

__global__ __launch_bounds__(256) void gru_mfma(
    float* __restrict__ h, ushort* __restrict__ hb, const float* __restrict__ agg,
    const ushort* __restrict__ Wrzg, const ushort* __restrict__ Wnig,
    const ushort* __restrict__ Wnhg,
    const float* __restrict__ bih, const float* __restrict__ bhh, int N) {
    __shared__ char lds[128 * WRZST + 2 * 64 * WNST];  // 51200 B
    int tid = threadIdx.x, w = tid >> 6, lane = tid & 63;
    int quad = lane >> 4, nrow = lane & 15;
    char* wrz = lds;
    char* wni = lds + 128 * WRZST;
    char* wnh = wni + 64 * WNST;

    // ---- stage weights (whole block) ----
    {
        int r = tid >> 1, half = tid & 1;
        const uint4* g = (const uint4*)(Wrzg + r * 128 + half * 64);
        uint4* d = (uint4*)(wrz + r * WRZST + half * 128);
#pragma unroll
        for (int i = 0; i < 8; i++) d[i] = g[i];
        if (tid < 128) {
            const uint4* g2 = (const uint4*)(Wnig + (tid >> 1) * 64 + (tid & 1) * 32);
            uint4* d2 = (uint4*)(wni + (tid >> 1) * WNST + (tid & 1) * 64);
#pragma unroll
            for (int i = 0; i < 4; i++) d2[i] = g2[i];
        } else {
            int t2 = tid - 128;
            const uint4* g2 = (const uint4*)(Wnhg + (t2 >> 1) * 64 + (t2 & 1) * 32);
            uint4* d2 = (uint4*)(wnh + (t2 >> 1) * WNST + (t2 & 1) * 64);
#pragma unroll
            for (int i = 0; i < 4; i++) d2[i] = g2[i];
        }
    }
    __syncthreads();

    int nb0 = blockIdx.x * 128 + w * 32;
    if (nb0 >= N) return;

    // biases -> accumulator init values (col = nt*16 + nrow)
    float brz[8], bi[4], bhv[4];
#pragma unroll
    for (int nt = 0; nt < 8; nt++) brz[nt] = bih[nt * 16 + nrow] + bhh[nt * 16 + nrow];
#pragma unroll
    for (int nt = 0; nt < 4; nt++) {
        bi[nt] = bih[128 + nt * 16 + nrow];
        bhv[nt] = bhh[128 + nt * 16 + nrow];
    }

    int n0 = min(nb0 + nrow, N - 1);
    int n1 = min(nb0 + 16 + nrow, N - 1);
    const float* ag0 = agg + (size_t)n0 * 64;
    const float* ag1 = agg + (size_t)n1 * 64;
    const ushort* hb0 = hb + (size_t)n0 * 64;
    const ushort* hb1 = hb + (size_t)n1 * 64;

    f32x4 accrz[2][8], acci[2][4], acch[2][4];
#pragma unroll
    for (int nt = 0; nt < 8; nt++) {
        f32x4 v; v[0] = v[1] = v[2] = v[3] = brz[nt];
        accrz[0][nt] = v; accrz[1][nt] = v;
    }
#pragma unroll
    for (int nt = 0; nt < 4; nt++) {
        f32x4 vi; vi[0] = vi[1] = vi[2] = vi[3] = bi[nt];
        acci[0][nt] = vi; acci[1][nt] = vi;
        f32x4 vh; vh[0] = vh[1] = vh[2] = vh[3] = bhv[nt];
        acch[0][nt] = vh; acch[1][nt] = vh;
    }

#pragma unroll
    for (int ks = 0; ks < 4; ks++) {
        bf16x8 a0, a1;
        if (ks < 2) {  // agg part (K 0..63)
            a0 = aggfrag(ag0, ks * 32 + quad * 8);
            a1 = aggfrag(ag1, ks * 32 + quad * 8);
        } else {  // h part (K 64..127)
            a0 = *(const bf16x8*)(hb0 + (ks - 2) * 32 + quad * 8);
            a1 = *(const bf16x8*)(hb1 + (ks - 2) * 32 + quad * 8);
        }
#pragma unroll
        for (int nt = 0; nt < 8; nt++) {
            bf16x8 b = *(const bf16x8*)(wrz + (nt * 16 + nrow) * WRZST + ks * 64 + quad * 16);
            accrz[0][nt] = MFMA16(a0, b, accrz[0][nt]);
            accrz[1][nt] = MFMA16(a1, b, accrz[1][nt]);
        }
        if (ks < 2) {
#pragma unroll
            for (int nt = 0; nt < 4; nt++) {
                bf16x8 b = *(const bf16x8*)(wni + (nt * 16 + nrow) * WNST + ks * 64 + quad * 16);
                acci[0][nt] = MFMA16(a0, b, acci[0][nt]);
                acci[1][nt] = MFMA16(a1, b, acci[1][nt]);
            }
        } else {
#pragma unroll
            for (int nt = 0; nt < 4; nt++) {
                bf16x8 b = *(const bf16x8*)(wnh + (nt * 16 + nrow) * WNST + (ks - 2) * 64 + quad * 16);
                acch[0][nt] = MFMA16(a0, b, acch[0][nt]);
                acch[1][nt] = MFMA16(a1, b, acch[1][nt]);
            }
        }
    }

    // ---- gates + h update (C-layout elementwise) ----
#pragma unroll
    for (int mt = 0; mt < 2; mt++)
#pragma unroll
        for (int nt = 0; nt < 4; nt++)
#pragma unroll
            for (int rg = 0; rg < 4; rg++) {
                int node = nb0 + mt * 16 + quad * 4 + rg;
                if (node < N) {
                    int col = nt * 16 + nrow;
                    float r = fast_sig(accrz[mt][nt][rg]);
                    float z = fast_sig(accrz[mt][nt + 4][rg]);
                    float nn = fast_tanh(acci[mt][nt][rg] + r * acch[mt][nt][rg]);
                    size_t idx = (size_t)node * 64 + col;
                    float ho = h[idx];
                    float hnew = (1.f - z) * nn + z * ho;
                    h[idx] = hnew;
                    hb[idx] = f2bf(hnew);
                }
            }
}

extern "C" void kernel_launch(void* const* d_in, const int* in_sizes, int n_in,
                              void* d_out, int out_size, void* d_ws, size_t ws_size,
                              hipStream_t stream) {
    const int* edge_index = (const int*)d_in[0];
    int E = in_sizes[0] / 2;
    const int* src = edge_index;
    const int* dst = edge_index + E;
    const int* kinds = (const int*)d_in[1];
    int N = in_sizes[1];
    const float* edge_attr = (const float*)d_in[2];
    const float* emb = (const float*)d_in[3];
    const float* msg_w1 = (const float*)d_in[4];
    const float* msg_b1 = (const float*)d_in[5];
    const float* msg_w2 = (const float*)d_in[6];
    const float* msg_b2 = (const float*)d_in[7];
    const float* gru_wih = (const float*)d_in[8];
    const float* gru_whh = (const float*)d_in[9];
    const float* gru_bih = (const float*)d_in[10];
    const float* gru_bhh = (const float*)d_in[11];
    const float* head_w1 = (const float*)d_in[12];
    const float* head_b1 = (const float*)d_in[13];
    const float* head_w2 = (const float*)d_in[14];
    const float* head_b2 = (const float*)d_in[15];
    float* out = (float*)d_out;

    // workspace carve-up
    char* p = (char*)d_ws;
    float* h = (float*)p;        p += (size_t)N * 64 * 4;
    float* agg = (float*)p;      p += (size_t)N * 64 * 4;
    int* deg = (int*)p;          p += (size_t)N * 4;
    int* cursor = (int*)p;       p += (size_t)N * 4;
    int* src_s = (int*)p;        p += (size_t)E * 4;
    int* dst_s = (int*)p;        p += (size_t)E * 4;
    ushort* hb = (ushort*)p;     p += (size_t)N * 64 * 2;
    ushort* Wb1 = (ushort*)p;    p += 30720 * 2;
    ushort* Wb2 = (ushort*)p;    p += 12288 * 2;
    ushort* Wh1 = (ushort*)p;    p += 10240 * 2;
    ushort* Wh2b = (ushort*)p;   p += 1024 * 2;
    ushort* Wrz = (ushort*)p;    p += 49152 * 2;
    ushort* Wni = (ushort*)p;    p += 12288 * 2;
    ushort* Wnh = (ushort*)p;    p += 12288 * 2;
    ushort* ea_sb = (ushort*)p;  p += (size_t)E * 4 * 2;

    int nchunks = (E + CHUNK - 1) / CHUNK;

    prep_kernel<<<500, 256, 0, stream>>>(msg_w1, msg_w2, gru_wih, gru_whh, head_w1,
                                         head_w2, Wb1, Wb2, Wh1, Wh2b, Wrz, Wni, Wnh);
    embed_kernel<<<(N * 64 + 255) / 256, 256, 0, stream>>>(h, hb, emb, kinds, N);

    hipMemsetAsync(deg, 0, (size_t)N * sizeof(int), stream);
    hist_kernel<<<(E + 255) / 256, 256, 0, stream>>>(dst, deg, E);
    scan_kernel<<<1, 1024, 0, stream>>>(deg, cursor, N);
    scatter_kernel<<<(E + 255) / 256, 256, 0, stream>>>(src, dst, edge_attr, cursor,
                                                        src_s, dst_s, ea_sb, E);

    for (int l = 0; l < 3; l++) {
        hipMemsetAsync(agg, 0, (size_t)N * 64 * sizeof(float), stream);
        edge_msg_mfma<<<512, 256, 0, stream>>>(
            hb, src_s, dst_s, ea_sb,
            Wb1 + l * 10240, Wb2 + l * 4096,
            msg_b1 + l * 64, msg_b2 + l * 64, agg, E, nchunks);
        gru_mfma<<<(N + 127) / 128, 256, 0, stream>>>(
            h, hb, agg, Wrz + l * 16384, Wni + l * 4096, Wnh + l * 4096,
            gru_bih + l * 192, gru_bhh + l * 192, N);
    }
    head_mfma<<<512, 256, 0, stream>>>(hb, src, dst, edge_attr, Wh1, Wh2b,
                                       head_b1, head_b2, out, E, nchunks);
}